// Round 12
// baseline (573.972 us; speedup 1.0000x reference)
//
#include <hip/hip_runtime.h>
#include <hip/hip_bf16.h>
#include <stdint.h>
#include <math.h>

typedef __attribute__((ext_vector_type(4))) float f32x4;
typedef __attribute__((ext_vector_type(8))) short s16x8;

typedef const __attribute__((address_space(1))) void* gas_ptr;
typedef __attribute__((address_space(3))) void* las_ptr;

__device__ __forceinline__ float bf2f(unsigned short u) {
    union { unsigned int i; float f; } x; x.i = ((unsigned int)u) << 16; return x.f;
}
__device__ __forceinline__ unsigned short f2bf(float f) {
    union { float f; unsigned int u; } x; x.f = f;
    unsigned int r = x.u + 0x7FFFu + ((x.u >> 16) & 1u);
    return (unsigned short)(r >> 16);
}

// ---------------- fp32 -> bf16, all 5 tensors in ONE launch ----------------
__global__ __launch_bounds__(256) void cvt5(const float* __restrict__ x,
                                            const float* __restrict__ wq,
                                            const float* __restrict__ wk,
                                            const float* __restrict__ wv,
                                            const float* __restrict__ wo,
                                            unsigned short* __restrict__ xb,
                                            unsigned short* __restrict__ wqb,
                                            unsigned short* __restrict__ wkb,
                                            unsigned short* __restrict__ wvb,
                                            unsigned short* __restrict__ wob) {
    int b = blockIdx.x;
    const float* src; unsigned short* dst; long off;
    if (b < 8192) {
        src = x; dst = xb; off = (long)b * 2048;
    } else {
        int w = (b - 8192) >> 11;
        off = (long)((b - 8192) & 2047) * 2048;
        src = (w == 0) ? wq : (w == 1) ? wk : (w == 2) ? wv : wo;
        dst = (w == 0) ? wqb : (w == 1) ? wkb : (w == 2) ? wvb : wob;
    }
    long i = off + threadIdx.x * 8;
    f32x4 a = *(const f32x4*)(src + i);
    f32x4 c = *(const f32x4*)(src + i + 4);
    s16x8 o;
    o[0] = (short)f2bf(a[0]); o[1] = (short)f2bf(a[1]);
    o[2] = (short)f2bf(a[2]); o[3] = (short)f2bf(a[3]);
    o[4] = (short)f2bf(c[0]); o[5] = (short)f2bf(c[1]);
    o[6] = (short)f2bf(c[2]); o[7] = (short)f2bf(c[3]);
    *(s16x8*)(dst + i) = o;
}

// ====== 256x256 bf16 GEMM, BK=32, packed 64KB LDS -> 2 blocks/CU ======
// r11 diagnosis: 132KB LDS -> 1 block/CU -> no cross-block overlap; all
// bubbles must be filled intra-block (plateau ~54% MfmaUtil). r12: BK=32 with
// PACKED regions -- 128 logical rows x 32 K stored as [64 phys][64] (two
// M-rows per 128B phys row) -> LDS = 2buf x {A,B} x 2sub x [64][64] = 64KB ->
// 2 blocks/CU. Cross-block overlap fills read-burst + vmcnt-drain windows.
// Swizzle: phys col = ((l&1)*32 + hi*8) ^ ((p&7)<<3); per-wave fragment read
// hits all 8 16B slots of each 128B row exactly once (conflict-free).
// Staging: 1 glds/thread/region, linear dest; source pre-swizzled (rule 21).
// K-loop: r10 cross-barrier pipeline -- held H1 MFMA cluster issues right
// after the barrier, overlapping the next read burst; STAGE at tile top for
// max vmcnt issue-to-wait distance; 1 barrier per K-tile.
// MODE 1: z in {0,1,2} selects {Wq->Q, Wk->K, Wv->Vt}; z==2 writes V^T via a
// chunked LDS bounce (4 x 64-dim chunks through the 64KB buffer).
template <typename CT, int MODE>
__global__ __launch_bounds__(512, 2)
void gemm256_bt(const unsigned short* __restrict__ A,
                const unsigned short* __restrict__ B0,
                const unsigned short* __restrict__ B1,
                const unsigned short* __restrict__ B2,
                CT* __restrict__ C0, CT* __restrict__ C1, CT* __restrict__ C2,
                int N, int K, int nt,
                long sA, long sB, long sC, float alpha)
{
    const unsigned short* B = B0;
    CT* C = C0;
    if constexpr (MODE == 1) {
        if (blockIdx.z == 1)      { B = B1; C = C1; }
        else if (blockIdx.z == 2) { B = B2; C = C2; }
    } else {
        A += (long)blockIdx.z * sA;
        B += (long)blockIdx.z * sB;
        C += (long)blockIdx.z * sC;
    }

    __shared__ unsigned short Lds[2][2][2][64][64];   // 64 KiB

    const int t    = threadIdx.x;
    const int lane = t & 63;
    const int wid  = t >> 6;        // 0..7
    const int wm   = wid >> 2;      // 0..1
    const int wn   = wid & 3;       // 0..3

    // T1: XCD swizzle on x (gridDim.x % 8 == 0 for all our grids)
    const int cpx = (int)gridDim.x >> 3;
    const int bx  = ((int)blockIdx.x & 7) * cpx + ((int)blockIdx.x >> 3);
    const long brow = (long)bx * 256;
    const long bcol = (long)blockIdx.y * 256;

    const int lr = lane & 15;
    const int hi = lane >> 4;            // 0..3
    // fragment phys col: ((l&1)*32 + hi*8) ^ ((p&7)<<3); p&7 == (lr>>1)&7
    const int cfrag = (((lr & 1) << 5) | (hi << 3)) ^ (((lr >> 1) & 7) << 3);
    const int prb   = lr >> 1;           // phys-row offset within 8-row group

    // ---- staging precompute: thread t -> phys (p, cg*8), swizzled source ----
    const int voff = t * 8;              // linear LDS elem offset in region
    const unsigned short* pA[2];
    const unsigned short* pB[2];
    {
        const unsigned short* Ab = A + brow * K;
        const unsigned short* Bb = B + bcol * K;
        int p  = t >> 3;
        int cg = t & 7;
        int cs = (cg * 8) ^ ((p & 7) << 3);   // pre-swizzled packed col
        int la = 2 * p + (cs >> 5);           // logical local row
        int ko = cs & 31;                     // k offset
        #pragma unroll
        for (int H = 0; H < 2; ++H) {
            long ga = (long)((la >> 6) * 128 + H * 64 + (la & 63));
            long gb = (long)((la >> 5) * 64  + H * 32 + (la & 31));
            pA[H] = Ab + ga * K + ko;
            pB[H] = Bb + gb * K + ko;
        }
    }

#define STAGE_A(H, KT) \
    __builtin_amdgcn_global_load_lds((gas_ptr)(pA[H] + (long)(KT) * 32), \
        (las_ptr)(&Lds[(KT) & 1][0][H][0][0] + voff), 16, 0, 0)
#define STAGE_B(H, KT) \
    __builtin_amdgcn_global_load_lds((gas_ptr)(pB[H] + (long)(KT) * 32), \
        (las_ptr)(&Lds[(KT) & 1][1][H][0][0] + voff), 16, 0, 0)
#define STAGE_ALL(KT) do { \
    STAGE_A(0, KT); STAGE_B(0, KT); STAGE_A(1, KT); STAGE_B(1, KT); \
} while (0)

#define LOAD_AF(DST, CUR, QM) do { \
    _Pragma("unroll") \
    for (int m = 0; m < 4; ++m) \
        DST[m] = *(const s16x8*)&Lds[CUR][0][QM][wm * 32 + m * 8 + prb][cfrag]; \
} while (0)
#define LOAD_BQ(DST, CUR, QN) do { \
    _Pragma("unroll") \
    for (int n = 0; n < 2; ++n) \
        DST[n] = *(const s16x8*)&Lds[CUR][1][QN][wn * 16 + n * 8 + prb][cfrag]; \
} while (0)
#define MFMA_Q(QM, QN, AF, BQ) do { \
    _Pragma("unroll") \
    for (int m = 0; m < 4; ++m) \
        _Pragma("unroll") \
        for (int n = 0; n < 2; ++n) \
            acc[(QM) * 4 + m][(QN) * 2 + n] = __builtin_amdgcn_mfma_f32_16x16x32_bf16( \
                AF[m], BQ[n], acc[(QM) * 4 + m][(QN) * 2 + n], 0, 0, 0); \
} while (0)

    f32x4 acc[8][4];
    #pragma unroll
    for (int m = 0; m < 8; ++m)
        #pragma unroll
        for (int n = 0; n < 4; ++n)
            acc[m][n] = {0.f, 0.f, 0.f, 0.f};

    s16x8 af0[4], af1[4], bq0[2], bq1[2];

    // ---- prologue: stage tile 0, drain, barrier ----
    STAGE_ALL(0);
    asm volatile("s_waitcnt vmcnt(0)" ::: "memory");
    __builtin_amdgcn_s_barrier();
    asm volatile("" ::: "memory");

    // ---- tile 0 (no held H1 yet) ----
    if (nt > 1) STAGE_ALL(1);
    LOAD_AF(af0, 0, 0);
    LOAD_BQ(bq0, 0, 0);
    LOAD_BQ(bq1, 0, 1);
    __builtin_amdgcn_s_setprio(1);
    MFMA_Q(0, 0, af0, bq0);
    MFMA_Q(0, 1, af0, bq1);
    __builtin_amdgcn_s_setprio(0);
    LOAD_AF(af1, 0, 1);
    asm volatile("s_waitcnt lgkmcnt(0)" ::: "memory");
    asm volatile("s_waitcnt vmcnt(0)" ::: "memory");
    __builtin_amdgcn_s_barrier();
    asm volatile("" ::: "memory");

    // ---- steady state: H1(kt-1) overlaps kt's read burst; stage at top ----
    for (int kt = 1; kt < nt; ++kt) {
        const int cur = kt & 1;
        if (kt + 1 < nt) STAGE_ALL(kt + 1);
        __builtin_amdgcn_s_setprio(1);
        MFMA_Q(1, 1, af1, bq1);
        MFMA_Q(1, 0, af1, bq0);
        __builtin_amdgcn_s_setprio(0);
        LOAD_AF(af0, cur, 0);
        LOAD_BQ(bq0, cur, 0);
        LOAD_BQ(bq1, cur, 1);
        __builtin_amdgcn_s_setprio(1);
        MFMA_Q(0, 0, af0, bq0);
        MFMA_Q(0, 1, af0, bq1);
        __builtin_amdgcn_s_setprio(0);
        LOAD_AF(af1, cur, 1);
        asm volatile("s_waitcnt lgkmcnt(0)" ::: "memory");
        asm volatile("s_waitcnt vmcnt(0)" ::: "memory");
        __builtin_amdgcn_s_barrier();
        asm volatile("" ::: "memory");
    }
    // ---- final held H1 ----
    MFMA_Q(1, 1, af1, bq1);
    MFMA_Q(1, 0, af1, bq0);
#undef STAGE_A
#undef STAGE_B
#undef STAGE_ALL
#undef LOAD_AF
#undef LOAD_BQ
#undef MFMA_Q

    bool transposed = false;
    if constexpr (MODE == 1) transposed = (blockIdx.z == 2);

    if (transposed) {
        // ---- V^T epilogue: 4 chunks of 64 dims through the 64KB buffer ----
        unsigned short (*T)[264] = (unsigned short (*)[264])&Lds[0][0][0][0][0]; // 33792B
        const int  bz = (int)(brow >> 12);
        const long s0 = brow & 4095;
        unsigned short* vt = (unsigned short*)C + (long)bz * 2048 * 4096;
        #pragma unroll
        for (int dc = 0; dc < 4; ++dc) {
            __syncthreads();
            if (wn == dc) {
                #pragma unroll
                for (int m = 0; m < 8; ++m)
                    #pragma unroll
                    for (int n = 0; n < 4; ++n)
                        #pragma unroll
                        for (int i = 0; i < 4; ++i)
                            T[n * 16 + lr][wm * 128 + m * 16 + hi * 4 + i] =
                                f2bf(acc[m][n][i]);
            }
            __syncthreads();
            const int d   = t >> 3;
            const int scc = (t & 7) * 32;
            #pragma unroll
            for (int j = 0; j < 4; ++j) {
                s16x8 v = *(const s16x8*)&T[d][scc + j * 8];
                *(s16x8*)(vt + (bcol + dc * 64 + d) * 4096L + s0 + scc + j * 8) = v;
            }
        }
    } else {
        // ---- normal C write: row = 16*am + hi*4 + i, col = 16*an + lr ----
        #pragma unroll
        for (int m = 0; m < 8; ++m) {
            #pragma unroll
            for (int n = 0; n < 4; ++n) {
                #pragma unroll
                for (int i = 0; i < 4; ++i) {
                    long row = brow + wm * 128 + m * 16 + hi * 4 + i;
                    long col = bcol + wn * 64 + n * 16 + lr;
                    float vv = acc[m][n][i] * alpha;
                    if constexpr (sizeof(CT) == 2) {
                        ((unsigned short*)C)[row * (long)N + col] = f2bf(vv);
                    } else {
                        ((float*)C)[row * (long)N + col] = vv;
                    }
                }
            }
        }
    }
}

// ---------------- row softmax, in place, bf16, ncols = 4096 ----------------
__global__ __launch_bounds__(256) void softmax_inplace(unsigned short* __restrict__ S, int ncols) {
    const long row = blockIdx.x;
    unsigned short* p = S + row * (long)ncols;
    const int t = threadIdx.x;
    const int wid = t >> 6;

    ushort4 raw[4];
    const ushort4* pv = (const ushort4*)(p + t * 16);
    #pragma unroll
    for (int i = 0; i < 4; ++i) raw[i] = pv[i];

    float v[16];
    float mx = -1e30f;
    #pragma unroll
    for (int i = 0; i < 4; ++i) {
        v[4*i+0] = bf2f(raw[i].x); v[4*i+1] = bf2f(raw[i].y);
        v[4*i+2] = bf2f(raw[i].z); v[4*i+3] = bf2f(raw[i].w);
    }
    #pragma unroll
    for (int i = 0; i < 16; ++i) mx = fmaxf(mx, v[i]);
    #pragma unroll
    for (int off = 32; off > 0; off >>= 1) mx = fmaxf(mx, __shfl_xor(mx, off));

    __shared__ float red[8];
    if ((t & 63) == 0) red[wid] = mx;
    __syncthreads();
    mx = fmaxf(fmaxf(red[0], red[1]), fmaxf(red[2], red[3]));

    float sum = 0.f;
    #pragma unroll
    for (int i = 0; i < 16; ++i) { v[i] = __expf(v[i] - mx); sum += v[i]; }
    #pragma unroll
    for (int off = 32; off > 0; off >>= 1) sum += __shfl_xor(sum, off);
    __syncthreads();
    if ((t & 63) == 0) red[4 + wid] = sum;
    __syncthreads();
    sum = red[4] + red[5] + red[6] + red[7];
    const float inv = 1.0f / sum;

    ushort4* po = (ushort4*)(p + t * 16);
    #pragma unroll
    for (int i = 0; i < 4; ++i) {
        ushort4 o;
        o.x = f2bf(v[4*i+0] * inv); o.y = f2bf(v[4*i+1] * inv);
        o.z = f2bf(v[4*i+2] * inv); o.w = f2bf(v[4*i+3] * inv);
        po[i] = o;
    }
}

extern "C" void kernel_launch(void* const* d_in, const int* in_sizes, int n_in,
                              void* d_out, int out_size, void* d_ws, size_t ws_size,
                              hipStream_t stream) {
    const float* x  = (const float*)d_in[0];
    const float* wq = (const float*)d_in[1];
    const float* wk = (const float*)d_in[2];
    const float* wv = (const float*)d_in[3];
    const float* wo = (const float*)d_in[4];
    float* out = (float*)d_out;

    const long SDIM = 2048, SEQ = 4096, BATCH = 2;
    const long MS = BATCH * SEQ;       // 8192
    const long XN = MS * SDIM;         // 16,777,216
    const long WN = SDIM * SDIM;       // 4,194,304

    unsigned short* ws  = (unsigned short*)d_ws;
    unsigned short* Xbf = ws;
    unsigned short* Wqb = ws + XN;
    unsigned short* Wkb = Wqb + WN;
    unsigned short* Wvb = Wkb + WN;
    unsigned short* Wob = Wvb + WN;
    unsigned short* Qb  = Wob + WN;         // XN (reused as Ctx later)
    unsigned short* Kb  = Qb + XN;
    unsigned short* Vt  = Kb + XN;          // V^T, [2][2048][4096]
    unsigned short* Sb  = Vt + XN;          // 2*4096*4096 bf16
    unsigned short* Ctx = Qb;

    // fp32 -> bf16, one launch for all 5 tensors
    cvt5<<<16384, 256, 0, stream>>>(x, wq, wk, wv, wo, Xbf, Wqb, Wkb, Wvb, Wob);

    // Q,K,V^T projections in ONE dispatch
    dim3 gqkv((unsigned)(MS / 256), (unsigned)(SDIM / 256), 3);
    gemm256_bt<unsigned short, 1><<<gqkv, 512, 0, stream>>>(
        Xbf, Wqb, Wkb, Wvb, Qb, Kb, Vt,
        (int)SDIM, (int)SDIM, (int)(SDIM / 32), 0, 0, 0, 1.0f);

    // scores: S[b] = Q[b] @ K[b]^T * (1/sqrt(D))
    const float scale = 1.0f / sqrtf((float)SDIM);
    dim3 gs((unsigned)(SEQ / 256), (unsigned)(SEQ / 256), (unsigned)BATCH);
    gemm256_bt<unsigned short, 0><<<gs, 512, 0, stream>>>(
        Qb, Kb, nullptr, nullptr, Sb, nullptr, nullptr,
        (int)SEQ, (int)SDIM, (int)(SDIM / 32),
        SEQ * SDIM, SEQ * SDIM, SEQ * SEQ, scale);

    // softmax rows in place
    softmax_inplace<<<(int)(BATCH * SEQ), 256, 0, stream>>>(Sb, (int)SEQ);

    // ctx[b] = P[b] @ Vt[b]^T : M=SEQ, N=SDIM, K=SEQ (Ctx overwrites Qb)
    dim3 gc((unsigned)(SEQ / 256), (unsigned)(SDIM / 256), (unsigned)BATCH);
    gemm256_bt<unsigned short, 0><<<gc, 512, 0, stream>>>(
        Sb, Vt, nullptr, nullptr, Ctx, nullptr, nullptr,
        (int)SDIM, (int)SEQ, (int)(SEQ / 32),
        SEQ * SEQ, SDIM * SEQ, SEQ * SDIM, 1.0f);

    // out = Ctx @ Wo^T  (fp32 out, flat [8192,2048])
    dim3 gp((unsigned)(MS / 256), (unsigned)(SDIM / 256), 1);
    gemm256_bt<float, 0><<<gp, 512, 0, stream>>>(
        Ctx, Wob, nullptr, nullptr, out, nullptr, nullptr,
        (int)SDIM, (int)SDIM, (int)(SDIM / 32), 0, 0, 0, 1.0f);
}

// Round 13
// 565.596 us; speedup vs baseline: 1.0148x; 1.0148x over previous
//
#include <hip/hip_runtime.h>
#include <hip/hip_bf16.h>
#include <stdint.h>
#include <math.h>

typedef __attribute__((ext_vector_type(4)))  float f32x4;
typedef __attribute__((ext_vector_type(16))) float f32x16;
typedef __attribute__((ext_vector_type(8)))  short s16x8;

typedef const __attribute__((address_space(1))) void* gas_ptr;
typedef __attribute__((address_space(3))) void* las_ptr;

__device__ __forceinline__ float bf2f(unsigned short u) {
    union { unsigned int i; float f; } x; x.i = ((unsigned int)u) << 16; return x.f;
}
__device__ __forceinline__ unsigned short f2bf(float f) {
    union { float f; unsigned int u; } x; x.f = f;
    unsigned int r = x.u + 0x7FFFu + ((x.u >> 16) & 1u);
    return (unsigned short)(r >> 16);
}

// ---------------- fp32 -> bf16, all 5 tensors in ONE launch ----------------
__global__ __launch_bounds__(256) void cvt5(const float* __restrict__ x,
                                            const float* __restrict__ wq,
                                            const float* __restrict__ wk,
                                            const float* __restrict__ wv,
                                            const float* __restrict__ wo,
                                            unsigned short* __restrict__ xb,
                                            unsigned short* __restrict__ wqb,
                                            unsigned short* __restrict__ wkb,
                                            unsigned short* __restrict__ wvb,
                                            unsigned short* __restrict__ wob) {
    int b = blockIdx.x;
    const float* src; unsigned short* dst; long off;
    if (b < 8192) {
        src = x; dst = xb; off = (long)b * 2048;
    } else {
        int w = (b - 8192) >> 11;
        off = (long)((b - 8192) & 2047) * 2048;
        src = (w == 0) ? wq : (w == 1) ? wk : (w == 2) ? wv : wo;
        dst = (w == 0) ? wqb : (w == 1) ? wkb : (w == 2) ? wvb : wob;
    }
    long i = off + threadIdx.x * 8;
    f32x4 a = *(const f32x4*)(src + i);
    f32x4 c = *(const f32x4*)(src + i + 4);
    s16x8 o;
    o[0] = (short)f2bf(a[0]); o[1] = (short)f2bf(a[1]);
    o[2] = (short)f2bf(a[2]); o[3] = (short)f2bf(a[3]);
    o[4] = (short)f2bf(c[0]); o[5] = (short)f2bf(c[1]);
    o[6] = (short)f2bf(c[2]); o[7] = (short)f2bf(c[3]);
    *(s16x8*)(dst + i) = o;
}

// ====== 256x256 bf16 GEMM (r11 skeleton) with 32x32x16 MFMA ======
// r11 loop exactly (cross-barrier held-H1 pipeline, 1 barrier/K-tile, BK=64,
// 128KB LDS, T2 swizzle, T1 XCD swizzle). Changed ONLY the MFMA shape:
// v_mfma_f32_32x32x16_bf16 -- +15% peak pipe rate (2382 vs 2075 TF ubench),
// half the MFMA instruction count (32/wave/K-tile), same operand bytes.
// Layouts: A row = lane&31, k = (lane>>5)*8+i (K-doubling pattern verified on
// 16x16x32 in this kernel); B symmetric (col = lane&31); C/D col = lane&31,
// row = (reg&3) + 8*(reg>>2) + 4*(lane>>5), reg in [0,16)  [m74/m101 HW-verified].
// Wave tile 128x64 = 4 Mreps x 2 Nreps of 32x32; QM half = 2 Mreps.
// MODE 1: z in {0,1,2} -> {Wq->Q, Wk->K, Wv->Vt}; z==2 writes V^T via the
// LDS-bounce transposed epilogue (sm union, epilogue-only).
template <typename CT, int MODE>
__global__ __launch_bounds__(512, 2)
void gemm256_bt(const unsigned short* __restrict__ A,
                const unsigned short* __restrict__ B0,
                const unsigned short* __restrict__ B1,
                const unsigned short* __restrict__ B2,
                CT* __restrict__ C0, CT* __restrict__ C1, CT* __restrict__ C2,
                int N, int K, int nt,
                long sA, long sB, long sC, float alpha)
{
    const unsigned short* B = B0;
    CT* C = C0;
    if constexpr (MODE == 1) {
        if (blockIdx.z == 1)      { B = B1; C = C1; }
        else if (blockIdx.z == 2) { B = B2; C = C2; }
    } else {
        A += (long)blockIdx.z * sA;
        B += (long)blockIdx.z * sB;
        C += (long)blockIdx.z * sC;
    }

    __shared__ union {
        unsigned short L[2][2][2][128][64];   // 128 KiB loop buffers
        unsigned short T[256][264];           // transpose bounce (epilogue only)
    } sm;

    const int t    = threadIdx.x;
    const int lane = t & 63;
    const int wid  = t >> 6;        // 0..7
    const int wm   = wid >> 2;      // 0..1
    const int wn   = wid & 3;       // 0..3

    // T1: XCD swizzle on x (gridDim.x % 8 == 0 for all grids here)
    const int cpx = (int)gridDim.x >> 3;
    const int bx  = ((int)blockIdx.x & 7) * cpx + ((int)blockIdx.x >> 3);
    const long brow = (long)bx * 256;
    const long bcol = (long)blockIdx.y * 256;

    const int c31   = lane & 31;         // fragment row (A) / col (B) / col (C)
    const int khalf = lane >> 5;         // 0..1 -> k subgroup of 8
    const int sw8   = (lane & 7) << 3;   // T2 swizzle (element units), row&7 == lane&7

    // ---- staging precompute (UNCHANGED from r11): linear dest, swizzled src ----
    int voff[2];
    const unsigned short* pA[2][2];
    const unsigned short* pB[2][2];
    {
        const unsigned short* Ab = A + brow * K;
        const unsigned short* Bb = B + bcol * K;
        #pragma unroll
        for (int j = 0; j < 2; ++j) {
            int u  = t + 512 * j;
            int ix = u >> 3;
            int cg = u & 7;
            int cs = (cg * 8) ^ ((ix & 7) << 3);
            voff[j] = u * 8;
            long ra0 = ((long)(ix >> 6) << 7) | (0 << 6) | (ix & 63);
            long ra1 = ((long)(ix >> 6) << 7) | (1 << 6) | (ix & 63);
            long rb0 = ((long)(ix >> 5) << 6) | (0 << 5) | (ix & 31);
            long rb1 = ((long)(ix >> 5) << 6) | (1 << 5) | (ix & 31);
            pA[0][j] = Ab + ra0 * K + cs;
            pA[1][j] = Ab + ra1 * K + cs;
            pB[0][j] = Bb + rb0 * K + cs;
            pB[1][j] = Bb + rb1 * K + cs;
        }
    }

#define STAGE_A(H, KT) do { \
    _Pragma("unroll") \
    for (int j = 0; j < 2; ++j) \
        __builtin_amdgcn_global_load_lds((gas_ptr)(pA[H][j] + (long)(KT) * 64), \
            (las_ptr)(&sm.L[(KT) & 1][0][H][0][0] + voff[j]), 16, 0, 0); \
} while (0)
#define STAGE_B(H, KT) do { \
    _Pragma("unroll") \
    for (int j = 0; j < 2; ++j) \
        __builtin_amdgcn_global_load_lds((gas_ptr)(pB[H][j] + (long)(KT) * 64), \
            (las_ptr)(&sm.L[(KT) & 1][1][H][0][0] + voff[j]), 16, 0, 0); \
} while (0)
#define STAGE_ALL(KT) do { \
    STAGE_A(0, KT); STAGE_B(0, KT); STAGE_A(1, KT); STAGE_B(1, KT); \
} while (0)

// A fragments for half QM: [mrep 0..1][ks 0..3], row = wm*64 + mrep*32 + c31
#define LOAD_A32(DST, CUR, QM) do { \
    _Pragma("unroll") \
    for (int m = 0; m < 2; ++m) \
        _Pragma("unroll") \
        for (int ks = 0; ks < 4; ++ks) \
            DST[m][ks] = *(const s16x8*)&sm.L[CUR][0][QM][wm * 64 + m * 32 + c31][(ks * 16 + khalf * 8) ^ sw8]; \
} while (0)
// B fragments for region QN (= nrep): [ks 0..3], row = wn*32 + c31
#define LOAD_B32(DST, CUR, QN) do { \
    _Pragma("unroll") \
    for (int ks = 0; ks < 4; ++ks) \
        DST[ks] = *(const s16x8*)&sm.L[CUR][1][QN][wn * 32 + c31][(ks * 16 + khalf * 8) ^ sw8]; \
} while (0)
// 16 MFMA: half QMB (acc rows QMB*2 + m), both nreps, K=64
#define MFMA_H(QMB, AF) do { \
    _Pragma("unroll") \
    for (int ks = 0; ks < 4; ++ks) \
        _Pragma("unroll") \
        for (int m = 0; m < 2; ++m) { \
            acc[(QMB) * 2 + m][0] = __builtin_amdgcn_mfma_f32_32x32x16_bf16( \
                AF[m][ks], bq0[ks], acc[(QMB) * 2 + m][0], 0, 0, 0); \
            acc[(QMB) * 2 + m][1] = __builtin_amdgcn_mfma_f32_32x32x16_bf16( \
                AF[m][ks], bq1[ks], acc[(QMB) * 2 + m][1], 0, 0, 0); \
        } \
} while (0)

    f32x16 acc[4][2];
    #pragma unroll
    for (int m = 0; m < 4; ++m)
        #pragma unroll
        for (int n = 0; n < 2; ++n)
            #pragma unroll
            for (int e = 0; e < 16; ++e)
                acc[m][n][e] = 0.f;

    s16x8 af0[2][4], af1[2][4], bq0[4], bq1[4];

    // ---- prologue: stage tile 0, drain, barrier ----
    STAGE_ALL(0);
    asm volatile("s_waitcnt vmcnt(0)" ::: "memory");
    __builtin_amdgcn_s_barrier();
    asm volatile("" ::: "memory");

    // ---- tile 0 (no held H1 yet) ----
    LOAD_A32(af0, 0, 0);
    LOAD_B32(bq0, 0, 0);
    LOAD_B32(bq1, 0, 1);
    if (nt > 1) STAGE_ALL(1);
    __builtin_amdgcn_s_setprio(1);
    MFMA_H(0, af0);
    __builtin_amdgcn_s_setprio(0);
    LOAD_A32(af1, 0, 1);
    asm volatile("s_waitcnt vmcnt(0) lgkmcnt(0)" ::: "memory");
    __builtin_amdgcn_s_barrier();
    asm volatile("" ::: "memory");

    // ---- steady state: held H1(kt-1) overlaps kt's read burst ----
    for (int kt = 1; kt < nt; ++kt) {
        const int cur = kt & 1;
        __builtin_amdgcn_s_setprio(1);
        MFMA_H(1, af1);                 // pure-register, fills matrix pipe
        __builtin_amdgcn_s_setprio(0);
        LOAD_A32(af0, cur, 0);
        LOAD_B32(bq0, cur, 0);
        LOAD_B32(bq1, cur, 1);
        if (kt + 1 < nt) STAGE_ALL(kt + 1);
        __builtin_amdgcn_s_setprio(1);
        MFMA_H(0, af0);
        __builtin_amdgcn_s_setprio(0);
        LOAD_A32(af1, cur, 1);
        asm volatile("s_waitcnt vmcnt(0) lgkmcnt(0)" ::: "memory");
        __builtin_amdgcn_s_barrier();
        asm volatile("" ::: "memory");
    }
    // ---- final held H1 ----
    MFMA_H(1, af1);
#undef STAGE_A
#undef STAGE_B
#undef STAGE_ALL
#undef LOAD_A32
#undef LOAD_B32
#undef MFMA_H

    bool transposed = false;
    if constexpr (MODE == 1) transposed = (blockIdx.z == 2);

    // C/D mapping (32x32, m74/m101): col = c31, row = (reg&3)+8*(reg>>2)+4*khalf
    if (transposed) {
        __syncthreads();
        #pragma unroll
        for (int m = 0; m < 4; ++m)
            #pragma unroll
            for (int n = 0; n < 2; ++n)
                #pragma unroll
                for (int r = 0; r < 16; ++r)
                    sm.T[wn * 64 + n * 32 + c31]
                        [wm * 128 + m * 32 + (r & 3) + 8 * (r >> 2) + 4 * khalf] =
                        f2bf(acc[m][n][r]);
        __syncthreads();
        const int  bz = (int)(brow >> 12);
        const long s0 = brow & 4095;
        unsigned short* vt = (unsigned short*)C + (long)bz * 2048 * 4096;
        #pragma unroll
        for (int k = 0; k < 16; ++k) {
            int c = t + 512 * k;
            int d = c >> 5;
            int s = (c & 31) * 8;
            s16x8 v = *(const s16x8*)&sm.T[d][s];
            *(s16x8*)(vt + (bcol + d) * 4096L + s0 + s) = v;
        }
    } else {
        #pragma unroll
        for (int m = 0; m < 4; ++m) {
            #pragma unroll
            for (int n = 0; n < 2; ++n) {
                #pragma unroll
                for (int r = 0; r < 16; ++r) {
                    long row = brow + wm * 128 + m * 32 + (r & 3) + 8 * (r >> 2) + 4 * khalf;
                    long col = bcol + wn * 64 + n * 32 + c31;
                    float vv = acc[m][n][r] * alpha;
                    if constexpr (sizeof(CT) == 2) {
                        ((unsigned short*)C)[row * (long)N + col] = f2bf(vv);
                    } else {
                        ((float*)C)[row * (long)N + col] = vv;
                    }
                }
            }
        }
    }
}

// ---------------- row softmax, in place, bf16, ncols = 4096 ----------------
__global__ __launch_bounds__(256) void softmax_inplace(unsigned short* __restrict__ S, int ncols) {
    const long row = blockIdx.x;
    unsigned short* p = S + row * (long)ncols;
    const int t = threadIdx.x;
    const int wid = t >> 6;

    ushort4 raw[4];
    const ushort4* pv = (const ushort4*)(p + t * 16);
    #pragma unroll
    for (int i = 0; i < 4; ++i) raw[i] = pv[i];

    float v[16];
    float mx = -1e30f;
    #pragma unroll
    for (int i = 0; i < 4; ++i) {
        v[4*i+0] = bf2f(raw[i].x); v[4*i+1] = bf2f(raw[i].y);
        v[4*i+2] = bf2f(raw[i].z); v[4*i+3] = bf2f(raw[i].w);
    }
    #pragma unroll
    for (int i = 0; i < 16; ++i) mx = fmaxf(mx, v[i]);
    #pragma unroll
    for (int off = 32; off > 0; off >>= 1) mx = fmaxf(mx, __shfl_xor(mx, off));

    __shared__ float red[8];
    if ((t & 63) == 0) red[wid] = mx;
    __syncthreads();
    mx = fmaxf(fmaxf(red[0], red[1]), fmaxf(red[2], red[3]));

    float sum = 0.f;
    #pragma unroll
    for (int i = 0; i < 16; ++i) { v[i] = __expf(v[i] - mx); sum += v[i]; }
    #pragma unroll
    for (int off = 32; off > 0; off >>= 1) sum += __shfl_xor(sum, off);
    __syncthreads();
    if ((t & 63) == 0) red[4 + wid] = sum;
    __syncthreads();
    sum = red[4] + red[5] + red[6] + red[7];
    const float inv = 1.0f / sum;

    ushort4* po = (ushort4*)(p + t * 16);
    #pragma unroll
    for (int i = 0; i < 4; ++i) {
        ushort4 o;
        o.x = f2bf(v[4*i+0] * inv); o.y = f2bf(v[4*i+1] * inv);
        o.z = f2bf(v[4*i+2] * inv); o.w = f2bf(v[4*i+3] * inv);
        po[i] = o;
    }
}

extern "C" void kernel_launch(void* const* d_in, const int* in_sizes, int n_in,
                              void* d_out, int out_size, void* d_ws, size_t ws_size,
                              hipStream_t stream) {
    const float* x  = (const float*)d_in[0];
    const float* wq = (const float*)d_in[1];
    const float* wk = (const float*)d_in[2];
    const float* wv = (const float*)d_in[3];
    const float* wo = (const float*)d_in[4];
    float* out = (float*)d_out;

    const long SDIM = 2048, SEQ = 4096, BATCH = 2;
    const long MS = BATCH * SEQ;       // 8192
    const long XN = MS * SDIM;         // 16,777,216
    const long WN = SDIM * SDIM;       // 4,194,304

    unsigned short* ws  = (unsigned short*)d_ws;
    unsigned short* Xbf = ws;
    unsigned short* Wqb = ws + XN;
    unsigned short* Wkb = Wqb + WN;
    unsigned short* Wvb = Wkb + WN;
    unsigned short* Wob = Wvb + WN;
    unsigned short* Qb  = Wob + WN;         // XN (reused as Ctx later)
    unsigned short* Kb  = Qb + XN;
    unsigned short* Vt  = Kb + XN;          // V^T, [2][2048][4096]
    unsigned short* Sb  = Vt + XN;          // 2*4096*4096 bf16
    unsigned short* Ctx = Qb;

    // fp32 -> bf16, one launch for all 5 tensors
    cvt5<<<16384, 256, 0, stream>>>(x, wq, wk, wv, wo, Xbf, Wqb, Wkb, Wvb, Wob);

    // Q,K,V^T projections in ONE dispatch
    dim3 gqkv((unsigned)(MS / 256), (unsigned)(SDIM / 256), 3);
    gemm256_bt<unsigned short, 1><<<gqkv, 512, 0, stream>>>(
        Xbf, Wqb, Wkb, Wvb, Qb, Kb, Vt,
        (int)SDIM, (int)SDIM, (int)(SDIM / 64), 0, 0, 0, 1.0f);

    // scores: S[b] = Q[b] @ K[b]^T * (1/sqrt(D))
    const float scale = 1.0f / sqrtf((float)SDIM);
    dim3 gs((unsigned)(SEQ / 256), (unsigned)(SEQ / 256), (unsigned)BATCH);
    gemm256_bt<unsigned short, 0><<<gs, 512, 0, stream>>>(
        Qb, Kb, nullptr, nullptr, Sb, nullptr, nullptr,
        (int)SEQ, (int)SDIM, (int)(SDIM / 64),
        SEQ * SDIM, SEQ * SDIM, SEQ * SEQ, scale);

    // softmax rows in place
    softmax_inplace<<<(int)(BATCH * SEQ), 256, 0, stream>>>(Sb, (int)SEQ);

    // ctx[b] = P[b] @ Vt[b]^T : M=SEQ, N=SDIM, K=SEQ (Ctx overwrites Qb)
    dim3 gc((unsigned)(SEQ / 256), (unsigned)(SDIM / 256), (unsigned)BATCH);
    gemm256_bt<unsigned short, 0><<<gc, 512, 0, stream>>>(
        Sb, Vt, nullptr, nullptr, Ctx, nullptr, nullptr,
        (int)SDIM, (int)SEQ, (int)(SEQ / 64),
        SEQ * SEQ, SDIM * SEQ, SEQ * SDIM, 1.0f);

    // out = Ctx @ Wo^T  (fp32 out, flat [8192,2048])
    dim3 gp((unsigned)(MS / 256), (unsigned)(SDIM / 256), 1);
    gemm256_bt<float, 0><<<gp, 512, 0, stream>>>(
        Ctx, Wob, nullptr, nullptr, out, nullptr, nullptr,
        (int)SDIM, (int)SDIM, (int)(SDIM / 64), 0, 0, 0, 1.0f);
}